// Round 6
// baseline (655.189 us; speedup 1.0000x reference)
//
#include <hip/hip_runtime.h>
#include <hip/hip_bf16.h>

#define DEV static __device__ __forceinline__

typedef __attribute__((ext_vector_type(8))) _Float16 half8;   // A/B frag: 8 fp16 = 4 VGPR
typedef __attribute__((ext_vector_type(4))) float f32x4;      // C/D frag

constexpr int Bc = 4, Tc = 2048, Dc = 2048, Hc = 16;          // HD = 128

DEV ushort f2h(float f) { _Float16 h = (_Float16)f; return __builtin_bit_cast(ushort, h); }
DEV float  h2f(ushort u) { return (float)__builtin_bit_cast(_Float16, u); }

DEV f32x4 MFMA(half8 a, half8 b, f32x4 c) {
  return __builtin_amdgcn_mfma_f32_16x16x32_f16(a, b, c, 0, 0, 0);
}

DEV void async_cp16(void* lds, const void* g) {
  __builtin_amdgcn_global_load_lds((const __attribute__((address_space(1))) void*)g,
                                   (__attribute__((address_space(3))) void*)lds,
                                   16, 0, 0);
}

// ---------------- f32 -> fp16 convert ----------------
__global__ __launch_bounds__(256) void cvt(const float* __restrict__ in,
                                           ushort* __restrict__ out, int n4) {
  const int i = blockIdx.x * 256 + threadIdx.x;
  if (i >= n4) return;
  const float4 v = ((const float4*)in)[i];
  ushort4 o;
  o.x = f2h(v.x); o.y = f2h(v.y); o.z = f2h(v.z); o.w = f2h(v.w);
  ((ushort4*)out)[i] = o;
}

// ---------------- GEMM: C[m][n] = sum_k A[m][k] * W[n][k] ----------------
// 128x128 tile, BK=32, 4 waves (2x2), global_load_lds staging, 16 MFMA/K-step.
template <typename OutT>
__global__ __launch_bounds__(256) void gemm_bt(const ushort* __restrict__ A,
                                               const ushort* __restrict__ Bw,
                                               OutT* __restrict__ C) {
  __shared__ ushort As[128 * 32];
  __shared__ ushort Bs[128 * 32];
  const int tid = threadIdx.x;
  const int lane = tid & 63, wid = tid >> 6;
  const int g = lane >> 4, q16 = lane & 15;
  const int wm = wid >> 1, wn = wid & 1;
  const int bm = blockIdx.y, bn = blockIdx.x;
  const ushort* Ab = A + (size_t)bm * 128 * Dc;
  const ushort* Bb = Bw + (size_t)bn * 128 * Dc;

  f32x4 acc[4][4] = {};

  for (int k0 = 0; k0 < Dc; k0 += 32) {
    __syncthreads();
#pragma unroll
    for (int q = 0; q < 2; ++q) {
      const int c = q * 256 + tid;
      const int row = c >> 2, col = (c & 3) << 3;
      const int ldsbase = (q * 256 + wid * 64) * 8;
      async_cp16(&As[ldsbase], Ab + (size_t)row * Dc + k0 + col);
      async_cp16(&Bs[ldsbase], Bb + (size_t)row * Dc + k0 + col);
    }
    __syncthreads();
    half8 a[4], b[4];
#pragma unroll
    for (int i = 0; i < 4; ++i)
      a[i] = *(const half8*)&As[(wm * 64 + i * 16 + q16) * 32 + g * 8];
#pragma unroll
    for (int j = 0; j < 4; ++j)
      b[j] = *(const half8*)&Bs[(wn * 64 + j * 16 + q16) * 32 + g * 8];
#pragma unroll
    for (int i = 0; i < 4; ++i)
#pragma unroll
      for (int j = 0; j < 4; ++j)
        acc[i][j] = MFMA(a[i], b[j], acc[i][j]);
  }

  const int m00 = bm * 128 + wm * 64 + g * 4;
  const int n0 = bn * 128 + wn * 64 + q16;
#pragma unroll
  for (int i = 0; i < 4; ++i)
#pragma unroll
    for (int j = 0; j < 4; ++j) {
      const int m0 = m00 + i * 16;
      const int n = n0 + j * 16;
#pragma unroll
      for (int r = 0; r < 4; ++r) {
        const float v = acc[i][j][r];
        if constexpr (sizeof(OutT) == 2)
          C[(size_t)(m0 + r) * Dc + n] = (OutT)f2h(v);
        else
          C[(size_t)(m0 + r) * Dc + n] = (OutT)v;
      }
    }
}

// ---------------- RoPE in-place on [B,T,H,128] fp16 ----------------
__global__ __launch_bounds__(256) void rope(ushort* __restrict__ X,
                                            const float* __restrict__ cs,
                                            const float* __restrict__ sn) {
  const int tid = blockIdx.x * 256 + threadIdx.x;
  const int row = tid >> 4;
  const int jq = (tid & 15) << 2;
  const int t = (row >> 4) & (Tc - 1);
  ushort* base = X + (size_t)row * 128;
  const ushort4 lo = *(const ushort4*)(base + jq);
  const ushort4 hi = *(const ushort4*)(base + 64 + jq);
  const float4 c4 = *(const float4*)(cs + t * 128 + jq);
  const float4 s4 = *(const float4*)(sn + t * 128 + jq);
  const float xl[4] = {h2f(lo.x), h2f(lo.y), h2f(lo.z), h2f(lo.w)};
  const float xh[4] = {h2f(hi.x), h2f(hi.y), h2f(hi.z), h2f(hi.w)};
  const float cc[4] = {c4.x, c4.y, c4.z, c4.w};
  const float ss[4] = {s4.x, s4.y, s4.z, s4.w};
  ushort4 olo, ohi;
  ushort* po = (ushort*)&olo;
  ushort* ph = (ushort*)&ohi;
#pragma unroll
  for (int k = 0; k < 4; ++k) {
    po[k] = f2h(xl[k] * cc[k] - xh[k] * ss[k]);
    ph[k] = f2h(xh[k] * cc[k] + xl[k] * ss[k]);
  }
  *(ushort4*)(base + jq) = olo;
  *(ushort4*)(base + 64 + jq) = ohi;
}

// ---------------- causal flash attention ----------------
// grid (8, 64) = 512 blocks, 512 threads (8 waves x 16 q-rows = 128-row tile).
// Head-major XCD swizzle; paired q-tiles {15-qx, qx} -> uniform 34 kv-iters.
// LDS = 64KB (Ks+Vt dbuf only) -> 2 blocks/CU co-resident (16 waves).
// P redistribution fully in-register via shfl_xor{16,32,48} (no Pt LDS).
// T13 defer-max; per-lane partial l (epilogue reduction). T14 V-stage split.
__global__ __launch_bounds__(512, 2) void attn(const ushort* __restrict__ Q,
                                               const ushort* __restrict__ K,
                                               const ushort* __restrict__ V,
                                               ushort* __restrict__ O) {
  __shared__ ushort Ks[2][64 * 128];   // [kv][d], XOR-swizzled (granule ^= kv&7)
  __shared__ ushort Vt[2][128 * 64];   // [d][kv], XOR-swizzled rows

  const int tid = threadIdx.x;         // 0..511
  const int lane = tid & 63, wid = tid >> 6;   // wid 0..7
  const int g = lane >> 4, q16 = lane & 15;

  // head-major XCD swizzle: bijective (8,64) remap
  const int flat = (int)(blockIdx.x + 8 * blockIdx.y);
  const int xcd = flat & 7, idx = flat >> 3;          // idx 0..63
  const int bh = xcd + 8 * (idx & 7);                 // head-slot 0..63
  const int qx = idx >> 3;                            // q-tile pair id 0..7

  const int b = bh >> 4, h = bh & 15;
  const size_t headbase = ((size_t)b * Tc * Hc + h) * 128;  // t-stride = 2048
  const float SCL2 = 0.12751743f;      // log2(e)/sqrt(128)

  // V lane mapping: dc spans 4 values per wave -> 4-way max on Vt ds_writes.
  const int vdc = (wid & 3) * 4 + (lane & 3);         // 0..15: d = vdc*8..+7
  const int vkvp = (wid >> 2) * 16 + (lane >> 2);     // 0..31: kv pair

  uint4 vreg[2];

#define ISSUEK(KT, BUF) do {                                                   \
    const ushort* Kb_ = K + headbase + (size_t)(KT) * 64 * Dc;                 \
    _Pragma("unroll") for (int i_ = 0; i_ < 2; ++i_) {                         \
      const int c_ = i_ * 512 + tid;                                           \
      const int kv_ = c_ >> 4, gl_ = c_ & 15;                                  \
      async_cp16(&Ks[BUF][(i_ * 512 + wid * 64) * 8],                          \
                 Kb_ + (size_t)kv_ * Dc + ((gl_ ^ (kv_ & 7)) << 3));           \
    }                                                                          \
  } while (0)

#define LOADV(KT) do {                                                         \
    const ushort* p0_ = V + headbase + (size_t)((KT) * 64 + 2 * vkvp) * Dc +   \
                        vdc * 8;                                               \
    vreg[0] = *(const uint4*)p0_;                                              \
    vreg[1] = *(const uint4*)(p0_ + Dc);                                       \
  } while (0)

#define WRITEV(BUF) do {                                                       \
    const ushort* e0_ = (const ushort*)&vreg[0];                               \
    const ushort* e1_ = (const ushort*)&vreg[1];                               \
    _Pragma("unroll") for (int j_ = 0; j_ < 8; ++j_) {                         \
      const int d_ = vdc * 8 + j_;                                             \
      const unsigned w_ = (unsigned)e0_[j_] | ((unsigned)e1_[j_] << 16);       \
      *(unsigned*)&Vt[BUF][(d_ * 64 + 2 * vkvp) ^ ((d_ & 7) << 3)] = w_;       \
    }                                                                          \
  } while (0)

#pragma unroll 1
  for (int half = 0; half < 2; ++half) {
    const int q0 = (half ? qx : 15 - qx) * 128;
    const int qrow = q0 + wid * 16;
    const int nt = q0 / 64 + 2;

    // Q fragments (B-op: col=q=lane&15, k=d=g*8+j)
    half8 qreg[4];
#pragma unroll
    for (int ds = 0; ds < 4; ++ds)
      qreg[ds] = *(const half8*)(Q + headbase +
                 (size_t)(qrow + q16) * Dc + ds * 32 + g * 8);

    f32x4 oacc[8] = {};                // O^T frags: row=d (g*4+r), col=q
    float m_ = -1e30f, l_ = 0.f;       // l_ is per-lane PARTIAL (own 16 kv)

    __builtin_amdgcn_s_barrier();      // prior half done reading all LDS bufs
    __builtin_amdgcn_sched_barrier(0);
    ISSUEK(0, 0);
    LOADV(0);
    WRITEV(0);                         // compiler waits vmcnt for vreg here

#pragma unroll 1
    for (int kt = 0; kt < nt; ++kt) {
      const int cur = kt & 1;
      const int kv0 = kt * 64;
      asm volatile("s_waitcnt vmcnt(0) lgkmcnt(0)" ::: "memory");
      __builtin_amdgcn_s_barrier();
      __builtin_amdgcn_sched_barrier(0);
      if (kt + 1 < nt) {
        ISSUEK(kt + 1, cur ^ 1);
        LOADV(kt + 1);
      }

      if (kv0 <= qrow + 15) {          // wave-uniform (qrow depends on wid)
        const ushort* Ksb = Ks[cur];
        const ushort* Vtb = Vt[cur];
        // S^T = K Q^T
        f32x4 s[4] = {};
        __builtin_amdgcn_s_setprio(1);
#pragma unroll
        for (int ds = 0; ds < 4; ++ds) {
          half8 kf[4];
#pragma unroll
          for (int kvf = 0; kvf < 4; ++kvf) {
            const int kv = kvf * 16 + q16;
            kf[kvf] = *(const half8*)&Ksb[(kv * 128 + ds * 32 + g * 8) ^ ((kv & 7) << 3)];
          }
#pragma unroll
          for (int kvf = 0; kvf < 4; ++kvf)
            s[kvf] = MFMA(kf[kvf], qreg[ds], s[kvf]);
        }
        __builtin_amdgcn_s_setprio(0);
        // causal mask + running max (q = qrow+q16; kv = kv0+kvf*16+g*4+r)
        const bool notfull = (kv0 + 63) > qrow;
        const int qg = qrow + q16;
        float pmax = -1e30f;
#pragma unroll
        for (int kvf = 0; kvf < 4; ++kvf)
#pragma unroll
          for (int r = 0; r < 4; ++r) {
            float v = s[kvf][r];
            if (notfull && (kv0 + kvf * 16 + g * 4 + r) > qg) v = -1e30f;
            s[kvf][r] = v;
            pmax = fmaxf(pmax, v);
          }
        pmax = fmaxf(pmax, __shfl_xor(pmax, 16));
        pmax = fmaxf(pmax, __shfl_xor(pmax, 32));
        // T13 defer-max: skip rescale while max growth small (p <= 2^2.04)
        if (!__all(pmax <= m_ + 16.f)) {
          const float mn2 = fmaxf(m_, pmax);
          const float alpha = __builtin_exp2f((m_ - mn2) * SCL2);
          m_ = mn2;
          l_ *= alpha;
#pragma unroll
          for (int df = 0; df < 8; ++df)
            oacc[df] *= alpha;
        }
        const float mn = m_;
        // exp + pack: w[kvf][i] = fp16 pair (kv = kvf*16+g*4+2i, +1)
        uint w[4][2];
        float lsum = 0.f;
#pragma unroll
        for (int kvf = 0; kvf < 4; ++kvf) {
          const float p0 = __builtin_exp2f((s[kvf][0] - mn) * SCL2);
          const float p1 = __builtin_exp2f((s[kvf][1] - mn) * SCL2);
          const float p2 = __builtin_exp2f((s[kvf][2] - mn) * SCL2);
          const float p3 = __builtin_exp2f((s[kvf][3] - mn) * SCL2);
          lsum += (p0 + p1) + (p2 + p3);
          w[kvf][0] = (unsigned)f2h(p0) | ((unsigned)f2h(p1) << 16);
          w[kvf][1] = (unsigned)f2h(p2) | ((unsigned)f2h(p3) << 16);
        }
        l_ += lsum;                    // per-lane partial; reduced at epilogue
        // In-register P redistribution -> PV B-frags.
        // Target lane(g,q) dword m of block c: kv = c*32+g*8+2m from source
        // lane g_s = 2(g&1)+(m>>1), reg w[2c+(g>>1)][m&1].
        const bool ghi = g >= 2;
        const bool godd = (g & 1) != 0;
        uint sA[2][2], sB[2][2];
#pragma unroll
        for (int c = 0; c < 2; ++c)
#pragma unroll
          for (int i = 0; i < 2; ++i) {
            sA[c][i] = ghi ? w[2 * c + 1][i] : w[2 * c][i];
            sB[c][i] = ghi ? w[2 * c][i] : w[2 * c + 1][i];
          }
        uint x16[2][2], x32[2][2], x48[2][2];
#pragma unroll
        for (int c = 0; c < 2; ++c)
#pragma unroll
          for (int i = 0; i < 2; ++i) {
            x16[c][i] = __shfl_xor(sA[c][i], 16);
            x32[c][i] = __shfl_xor(sB[c][i], 32);
            x48[c][i] = __shfl_xor(sB[c][i], 48);
          }
        half8 pb[2];
#pragma unroll
        for (int c = 0; c < 2; ++c) {
          uint4 t;
          t.x = godd ? (ghi ? x16[c][0] : x48[c][0]) : (ghi ? x32[c][0] : sA[c][0]);
          t.y = godd ? (ghi ? x16[c][1] : x48[c][1]) : (ghi ? x32[c][1] : sA[c][1]);
          t.z = godd ? (ghi ? sA[c][0] : x32[c][0]) : (ghi ? x48[c][0] : x16[c][0]);
          t.w = godd ? (ghi ? sA[c][1] : x32[c][1]) : (ghi ? x48[c][1] : x16[c][1]);
          pb[c] = __builtin_bit_cast(half8, t);
        }
        // O^T += V^T P^T
        __builtin_amdgcn_s_setprio(1);
#pragma unroll
        for (int c = 0; c < 2; ++c) {
#pragma unroll
          for (int df = 0; df < 8; ++df) {
            const int d = df * 16 + q16;
            const half8 vf = *(const half8*)&Vtb[(d * 64 + c * 32 + g * 8) ^ ((d & 7) << 3)];
            oacc[df] = MFMA(vf, pb[c], oacc[df]);
          }
        }
        __builtin_amdgcn_s_setprio(0);
      }

      if (kt + 1 < nt) WRITEV(cur ^ 1);   // vreg vmcnt wait lands here, hidden
    }

    // epilogue: reduce per-lane l partials across g, then store O fp16
    {
      l_ += __shfl_xor(l_, 16);
      l_ += __shfl_xor(l_, 32);
      const float inv = 1.0f / l_;
      const int t = qrow + q16;
#pragma unroll
      for (int df = 0; df < 8; ++df) {
        const f32x4 v = oacc[df];
        ushort4 o;
        o.x = f2h(v[0] * inv); o.y = f2h(v[1] * inv);
        o.z = f2h(v[2] * inv); o.w = f2h(v[3] * inv);
        *(ushort4*)(O + headbase + (size_t)t * Dc + df * 16 + g * 4) = o;
      }
    }
  }
#undef ISSUEK
#undef LOADV
#undef WRITEV
}

extern "C" void kernel_launch(void* const* d_in, const int* in_sizes, int n_in,
                              void* d_out, int out_size, void* d_ws, size_t ws_size,
                              hipStream_t stream) {
  (void)in_sizes; (void)n_in; (void)out_size; (void)ws_size;
  const float* x  = (const float*)d_in[0];
  const float* cs = (const float*)d_in[1];
  const float* sn = (const float*)d_in[2];
  // d_in[3] = mask (unused: causal handled analytically)
  const float* Wq = (const float*)d_in[4];
  const float* Wk = (const float*)d_in[5];
  const float* Wv = (const float*)d_in[6];
  const float* Wo = (const float*)d_in[7];
  float* out = (float*)d_out;

  char* ws = (char*)d_ws;
  const size_t MB = 1024 * 1024;
  ushort* xb  = (ushort*)(ws);            // 32MB x fp16; reused as attn output O
  ushort* wqb = (ushort*)(ws + 32 * MB);
  ushort* wkb = (ushort*)(ws + 40 * MB);
  ushort* wvb = (ushort*)(ws + 48 * MB);
  ushort* wob = (ushort*)(ws + 56 * MB);
  ushort* Qr  = (ushort*)(ws + 64 * MB);  // 32MB each, [B,T,H,128] fp16
  ushort* Kr  = (ushort*)(ws + 96 * MB);
  ushort* Vr  = (ushort*)(ws + 128 * MB); // end: 160MB

  cvt<<<16384, 256, 0, stream>>>(x, xb, 4194304);
  cvt<<<4096, 256, 0, stream>>>(Wq, wqb, 1048576);
  cvt<<<4096, 256, 0, stream>>>(Wk, wkb, 1048576);
  cvt<<<4096, 256, 0, stream>>>(Wv, wvb, 1048576);
  cvt<<<4096, 256, 0, stream>>>(Wo, wob, 1048576);

  const dim3 gg(16, 64);
  gemm_bt<ushort><<<gg, 256, 0, stream>>>(xb, wqb, Qr);
  gemm_bt<ushort><<<gg, 256, 0, stream>>>(xb, wkb, Kr);
  gemm_bt<ushort><<<gg, 256, 0, stream>>>(xb, wvb, Vr);

  rope<<<8192, 256, 0, stream>>>(Qr, cs, sn);
  rope<<<8192, 256, 0, stream>>>(Kr, cs, sn);

  attn<<<dim3(8, 64), 512, 0, stream>>>(Qr, Kr, Vr, xb);

  gemm_bt<float><<<gg, 256, 0, stream>>>(xb, wob, out);
}

// Round 7
// 612.433 us; speedup vs baseline: 1.0698x; 1.0698x over previous
//
#include <hip/hip_runtime.h>
#include <hip/hip_bf16.h>

#define DEV static __device__ __forceinline__

typedef __attribute__((ext_vector_type(8))) _Float16 half8;   // A/B frag: 8 fp16 = 4 VGPR
typedef __attribute__((ext_vector_type(4))) float f32x4;      // C/D frag

constexpr int Bc = 4, Tc = 2048, Dc = 2048, Hc = 16;          // HD = 128

DEV ushort f2h(float f) { _Float16 h = (_Float16)f; return __builtin_bit_cast(ushort, h); }
DEV float  h2f(ushort u) { return (float)__builtin_bit_cast(_Float16, u); }

DEV f32x4 MFMA(half8 a, half8 b, f32x4 c) {
  return __builtin_amdgcn_mfma_f32_16x16x32_f16(a, b, c, 0, 0, 0);
}

DEV void async_cp16(void* lds, const void* g) {
  __builtin_amdgcn_global_load_lds((const __attribute__((address_space(1))) void*)g,
                                   (__attribute__((address_space(3))) void*)lds,
                                   16, 0, 0);
}

// ---------------- f32 -> fp16 convert ----------------
__global__ __launch_bounds__(256) void cvt(const float* __restrict__ in,
                                           ushort* __restrict__ out, int n4) {
  const int i = blockIdx.x * 256 + threadIdx.x;
  if (i >= n4) return;
  const float4 v = ((const float4*)in)[i];
  ushort4 o;
  o.x = f2h(v.x); o.y = f2h(v.y); o.z = f2h(v.z); o.w = f2h(v.w);
  ((ushort4*)out)[i] = o;
}

// ---------------- GEMM: C[m][n] = sum_k A[m][k] * W[n][k] ----------------
// 128x128 tile, BK=32, 4 waves (2x2), global_load_lds staging, 16 MFMA/K-step.
// XCD remap: xcd = flat&7 owns bn in {2*xcd, 2*xcd+1} (1MB of B -> L2-resident)
// and sweeps all bm -> B fetched ~once from HBM per XCD.
template <typename OutT>
__global__ __launch_bounds__(256) void gemm_bt(const ushort* __restrict__ A,
                                               const ushort* __restrict__ Bw,
                                               OutT* __restrict__ C) {
  __shared__ ushort As[128 * 32];
  __shared__ ushort Bs[128 * 32];
  const int tid = threadIdx.x;
  const int lane = tid & 63, wid = tid >> 6;
  const int g = lane >> 4, q16 = lane & 15;
  const int wm = wid >> 1, wn = wid & 1;
  const int flat = (int)(blockIdx.x + 16 * blockIdx.y);   // 0..1023
  const int xcd = flat & 7, idx = flat >> 3;              // idx 0..127
  const int bn = xcd * 2 + (idx & 1);                     // 0..15
  const int bm = idx >> 1;                                // 0..63
  const ushort* Ab = A + (size_t)bm * 128 * Dc;
  const ushort* Bb = Bw + (size_t)bn * 128 * Dc;

  f32x4 acc[4][4] = {};

  for (int k0 = 0; k0 < Dc; k0 += 32) {
    __syncthreads();
#pragma unroll
    for (int q = 0; q < 2; ++q) {
      const int c = q * 256 + tid;
      const int row = c >> 2, col = (c & 3) << 3;
      const int ldsbase = (q * 256 + wid * 64) * 8;
      async_cp16(&As[ldsbase], Ab + (size_t)row * Dc + k0 + col);
      async_cp16(&Bs[ldsbase], Bb + (size_t)row * Dc + k0 + col);
    }
    __syncthreads();
    half8 a[4], b[4];
#pragma unroll
    for (int i = 0; i < 4; ++i)
      a[i] = *(const half8*)&As[(wm * 64 + i * 16 + q16) * 32 + g * 8];
#pragma unroll
    for (int j = 0; j < 4; ++j)
      b[j] = *(const half8*)&Bs[(wn * 64 + j * 16 + q16) * 32 + g * 8];
#pragma unroll
    for (int i = 0; i < 4; ++i)
#pragma unroll
      for (int j = 0; j < 4; ++j)
        acc[i][j] = MFMA(a[i], b[j], acc[i][j]);
  }

  const int m00 = bm * 128 + wm * 64 + g * 4;
  const int n0 = bn * 128 + wn * 64 + q16;
#pragma unroll
  for (int i = 0; i < 4; ++i)
#pragma unroll
    for (int j = 0; j < 4; ++j) {
      const int m0 = m00 + i * 16;
      const int n = n0 + j * 16;
#pragma unroll
      for (int r = 0; r < 4; ++r) {
        const float v = acc[i][j][r];
        if constexpr (sizeof(OutT) == 2)
          C[(size_t)(m0 + r) * Dc + n] = (OutT)f2h(v);
        else
          C[(size_t)(m0 + r) * Dc + n] = (OutT)v;
      }
    }
}

// ---------------- RoPE in-place on [B,T,H,128] fp16 ----------------
__global__ __launch_bounds__(256) void rope(ushort* __restrict__ X,
                                            const float* __restrict__ cs,
                                            const float* __restrict__ sn) {
  const int tid = blockIdx.x * 256 + threadIdx.x;
  const int row = tid >> 4;
  const int jq = (tid & 15) << 2;
  const int t = (row >> 4) & (Tc - 1);
  ushort* base = X + (size_t)row * 128;
  const ushort4 lo = *(const ushort4*)(base + jq);
  const ushort4 hi = *(const ushort4*)(base + 64 + jq);
  const float4 c4 = *(const float4*)(cs + t * 128 + jq);
  const float4 s4 = *(const float4*)(sn + t * 128 + jq);
  const float xl[4] = {h2f(lo.x), h2f(lo.y), h2f(lo.z), h2f(lo.w)};
  const float xh[4] = {h2f(hi.x), h2f(hi.y), h2f(hi.z), h2f(hi.w)};
  const float cc[4] = {c4.x, c4.y, c4.z, c4.w};
  const float ss[4] = {s4.x, s4.y, s4.z, s4.w};
  ushort4 olo, ohi;
  ushort* po = (ushort*)&olo;
  ushort* ph = (ushort*)&ohi;
#pragma unroll
  for (int k = 0; k < 4; ++k) {
    po[k] = f2h(xl[k] * cc[k] - xh[k] * ss[k]);
    ph[k] = f2h(xh[k] * cc[k] + xl[k] * ss[k]);
  }
  *(ushort4*)(base + jq) = olo;
  *(ushort4*)(base + 64 + jq) = ohi;
}

// ---------------- causal flash attention (2 q-chains / wave) ----------------
// grid (4, 64) = 256 blocks (1/CU), 512 threads: 8 waves x 32 q-rows = 256-row
// supertile. Paired supertiles {7-p, p} -> uniform 36 kv-iters. Two independent
// q-chains (qf=0,1) per wave interleave softmax dependency stalls and share
// K/V LDS fragment reads (LDS reads per MFMA halve). Head-major XCD swizzle.
// LDS 64KB; in-register P redistribution; T13 defer-max; T14 V-stage split.
__global__ __launch_bounds__(512, 2) void attn(const ushort* __restrict__ Q,
                                               const ushort* __restrict__ K,
                                               const ushort* __restrict__ V,
                                               ushort* __restrict__ O) {
  __shared__ ushort Ks[2][64 * 128];   // [kv][d], XOR-swizzled (granule ^= kv&7)
  __shared__ ushort Vt[2][128 * 64];   // [d][kv], XOR-swizzled rows

  const int tid = threadIdx.x;         // 0..511
  const int lane = tid & 63, wid = tid >> 6;   // wid 0..7
  const int g = lane >> 4, q16 = lane & 15;

  // head-major XCD swizzle over 256 blocks
  const int flat = (int)(blockIdx.x + 4 * blockIdx.y);    // 0..255
  const int xcd = flat & 7, idx = flat >> 3;              // idx 0..31
  const int bh = xcd + 8 * (idx & 7);                     // head-slot 0..63
  const int pr = idx >> 3;                                // supertile pair 0..3

  const int b = bh >> 4, h = bh & 15;
  const size_t headbase = ((size_t)b * Tc * Hc + h) * 128;  // t-stride = 2048
  const float SCL2 = 0.12751743f;      // log2(e)/sqrt(128)

  // V lane mapping: dc spans 4 values per wave -> 4-way max on Vt ds_writes.
  const int vdc = (wid & 3) * 4 + (lane & 3);         // 0..15: d = vdc*8..+7
  const int vkvp = (wid >> 2) * 16 + (lane >> 2);     // 0..31: kv pair

  uint4 vreg[2];

#define ISSUEK(KT, BUF) do {                                                   \
    const ushort* Kb_ = K + headbase + (size_t)(KT) * 64 * Dc;                 \
    _Pragma("unroll") for (int i_ = 0; i_ < 2; ++i_) {                         \
      const int c_ = i_ * 512 + tid;                                           \
      const int kv_ = c_ >> 4, gl_ = c_ & 15;                                  \
      async_cp16(&Ks[BUF][(i_ * 512 + wid * 64) * 8],                          \
                 Kb_ + (size_t)kv_ * Dc + ((gl_ ^ (kv_ & 7)) << 3));           \
    }                                                                          \
  } while (0)

#define LOADV(KT) do {                                                         \
    const ushort* p0_ = V + headbase + (size_t)((KT) * 64 + 2 * vkvp) * Dc +   \
                        vdc * 8;                                               \
    vreg[0] = *(const uint4*)p0_;                                              \
    vreg[1] = *(const uint4*)(p0_ + Dc);                                       \
  } while (0)

#define WRITEV(BUF) do {                                                       \
    const ushort* e0_ = (const ushort*)&vreg[0];                               \
    const ushort* e1_ = (const ushort*)&vreg[1];                               \
    _Pragma("unroll") for (int j_ = 0; j_ < 8; ++j_) {                         \
      const int d_ = vdc * 8 + j_;                                             \
      const unsigned w_ = (unsigned)e0_[j_] | ((unsigned)e1_[j_] << 16);       \
      *(unsigned*)&Vt[BUF][(d_ * 64 + 2 * vkvp) ^ ((d_ & 7) << 3)] = w_;       \
    }                                                                          \
  } while (0)

#pragma unroll 1
  for (int half = 0; half < 2; ++half) {
    const int q0 = (half ? pr : 7 - pr) * 256;
    const int qrow = q0 + wid * 32;          // wave owns rows qrow..qrow+31
    const int nt = q0 / 64 + 4;

    // Q fragments, 2 chains (B-op: col=q=lane&15, k=d=g*8+j)
    half8 qreg[2][4];
#pragma unroll
    for (int qf = 0; qf < 2; ++qf)
#pragma unroll
      for (int ds = 0; ds < 4; ++ds)
        qreg[qf][ds] = *(const half8*)(Q + headbase +
                       (size_t)(qrow + qf * 16 + q16) * Dc + ds * 32 + g * 8);

    f32x4 oacc[2][8] = {};             // O^T frags: row=d (g*4+r), col=q
    float m_[2] = {-1e30f, -1e30f};
    float l_[2] = {0.f, 0.f};          // per-lane partials

    __builtin_amdgcn_s_barrier();      // prior half done reading all LDS bufs
    __builtin_amdgcn_sched_barrier(0);
    ISSUEK(0, 0);
    LOADV(0);
    WRITEV(0);                         // compiler waits vmcnt for vreg here

#pragma unroll 1
    for (int kt = 0; kt < nt; ++kt) {
      const int cur = kt & 1;
      const int kv0 = kt * 64;
      asm volatile("s_waitcnt vmcnt(0) lgkmcnt(0)" ::: "memory");
      __builtin_amdgcn_s_barrier();
      __builtin_amdgcn_sched_barrier(0);
      if (kt + 1 < nt) {
        ISSUEK(kt + 1, cur ^ 1);
        LOADV(kt + 1);
      }

      if (kv0 <= qrow + 31) {          // wave-uniform
        const ushort* Ksb = Ks[cur];
        const ushort* Vtb = Vt[cur];
        // S^T = K Q^T, both chains share kf
        f32x4 s[2][4] = {};
        __builtin_amdgcn_s_setprio(1);
#pragma unroll
        for (int ds = 0; ds < 4; ++ds) {
          half8 kf[4];
#pragma unroll
          for (int kvf = 0; kvf < 4; ++kvf) {
            const int kv = kvf * 16 + q16;
            kf[kvf] = *(const half8*)&Ksb[(kv * 128 + ds * 32 + g * 8) ^ ((kv & 7) << 3)];
          }
#pragma unroll
          for (int kvf = 0; kvf < 4; ++kvf)
#pragma unroll
            for (int qf = 0; qf < 2; ++qf)
              s[qf][kvf] = MFMA(kf[kvf], qreg[qf][ds], s[qf][kvf]);
        }
        __builtin_amdgcn_s_setprio(0);
        // causal mask + running max; mask only on diagonal tiles (uniform branch)
        float pmax[2] = {-1e30f, -1e30f};
        if (kv0 + 63 > qrow) {
#pragma unroll
          for (int qf = 0; qf < 2; ++qf) {
            const int qg = qrow + qf * 16 + q16;
#pragma unroll
            for (int kvf = 0; kvf < 4; ++kvf)
#pragma unroll
              for (int r = 0; r < 4; ++r) {
                float v = s[qf][kvf][r];
                if ((kv0 + kvf * 16 + g * 4 + r) > qg) v = -1e30f;
                s[qf][kvf][r] = v;
                pmax[qf] = fmaxf(pmax[qf], v);
              }
          }
        } else {
#pragma unroll
          for (int qf = 0; qf < 2; ++qf)
#pragma unroll
            for (int kvf = 0; kvf < 4; ++kvf)
#pragma unroll
              for (int r = 0; r < 4; ++r)
                pmax[qf] = fmaxf(pmax[qf], s[qf][kvf][r]);
        }
#pragma unroll
        for (int qf = 0; qf < 2; ++qf) {
          pmax[qf] = fmaxf(pmax[qf], __shfl_xor(pmax[qf], 16));
          pmax[qf] = fmaxf(pmax[qf], __shfl_xor(pmax[qf], 32));
        }
        // T13 defer-max (joint trigger; rescaling a non-growing chain is benign)
        if (!__all((pmax[0] <= m_[0] + 16.f) & (pmax[1] <= m_[1] + 16.f))) {
#pragma unroll
          for (int qf = 0; qf < 2; ++qf) {
            const float mn2 = fmaxf(m_[qf], pmax[qf]);
            const float alpha = __builtin_exp2f((m_[qf] - mn2) * SCL2);
            m_[qf] = mn2;
            l_[qf] *= alpha;
#pragma unroll
            for (int df = 0; df < 8; ++df)
              oacc[qf][df] *= alpha;
          }
        }
        // exp + pack, both chains
        uint w[2][4][2];
#pragma unroll
        for (int qf = 0; qf < 2; ++qf) {
          const float mn = m_[qf];
          float lsum = 0.f;
#pragma unroll
          for (int kvf = 0; kvf < 4; ++kvf) {
            const float p0 = __builtin_exp2f((s[qf][kvf][0] - mn) * SCL2);
            const float p1 = __builtin_exp2f((s[qf][kvf][1] - mn) * SCL2);
            const float p2 = __builtin_exp2f((s[qf][kvf][2] - mn) * SCL2);
            const float p3 = __builtin_exp2f((s[qf][kvf][3] - mn) * SCL2);
            lsum += (p0 + p1) + (p2 + p3);
            w[qf][kvf][0] = (unsigned)f2h(p0) | ((unsigned)f2h(p1) << 16);
            w[qf][kvf][1] = (unsigned)f2h(p2) | ((unsigned)f2h(p3) << 16);
          }
          l_[qf] += lsum;
        }
        // In-register P redistribution -> PV B-frags (per chain).
        // Target lane(g,q) dword m of block c: kv = c*32+g*8+2m from source
        // lane g_s = 2(g&1)+(m>>1), reg w[2c+(g>>1)][m&1].
        const bool ghi = g >= 2;
        const bool godd = (g & 1) != 0;
        half8 pb[2][2];
#pragma unroll
        for (int qf = 0; qf < 2; ++qf) {
          uint sA[2][2], sB[2][2];
#pragma unroll
          for (int c = 0; c < 2; ++c)
#pragma unroll
            for (int i = 0; i < 2; ++i) {
              sA[c][i] = ghi ? w[qf][2 * c + 1][i] : w[qf][2 * c][i];
              sB[c][i] = ghi ? w[qf][2 * c][i] : w[qf][2 * c + 1][i];
            }
          uint x16[2][2], x32[2][2], x48[2][2];
#pragma unroll
          for (int c = 0; c < 2; ++c)
#pragma unroll
            for (int i = 0; i < 2; ++i) {
              x16[c][i] = __shfl_xor(sA[c][i], 16);
              x32[c][i] = __shfl_xor(sB[c][i], 32);
              x48[c][i] = __shfl_xor(sB[c][i], 48);
            }
#pragma unroll
          for (int c = 0; c < 2; ++c) {
            uint4 t;
            t.x = godd ? (ghi ? x16[c][0] : x48[c][0]) : (ghi ? x32[c][0] : sA[c][0]);
            t.y = godd ? (ghi ? x16[c][1] : x48[c][1]) : (ghi ? x32[c][1] : sA[c][1]);
            t.z = godd ? (ghi ? sA[c][0] : x32[c][0]) : (ghi ? x48[c][0] : x16[c][0]);
            t.w = godd ? (ghi ? sA[c][1] : x32[c][1]) : (ghi ? x48[c][1] : x16[c][1]);
            pb[qf][c] = __builtin_bit_cast(half8, t);
          }
        }
        // O^T += V^T P^T, both chains share vf
        __builtin_amdgcn_s_setprio(1);
#pragma unroll
        for (int c = 0; c < 2; ++c) {
#pragma unroll
          for (int df = 0; df < 8; ++df) {
            const int d = df * 16 + q16;
            const half8 vf = *(const half8*)&Vtb[(d * 64 + c * 32 + g * 8) ^ ((d & 7) << 3)];
#pragma unroll
            for (int qf = 0; qf < 2; ++qf)
              oacc[qf][df] = MFMA(vf, pb[qf][c], oacc[qf][df]);
          }
        }
        __builtin_amdgcn_s_setprio(0);
      }

      if (kt + 1 < nt) WRITEV(cur ^ 1);   // vreg vmcnt wait lands here, hidden
    }

    // epilogue: reduce per-lane l partials, store O fp16
#pragma unroll
    for (int qf = 0; qf < 2; ++qf) {
      float l = l_[qf];
      l += __shfl_xor(l, 16);
      l += __shfl_xor(l, 32);
      const float inv = 1.0f / l;
      const int t = qrow + qf * 16 + q16;
#pragma unroll
      for (int df = 0; df < 8; ++df) {
        const f32x4 v = oacc[qf][df];
        ushort4 o;
        o.x = f2h(v[0] * inv); o.y = f2h(v[1] * inv);
        o.z = f2h(v[2] * inv); o.w = f2h(v[3] * inv);
        *(ushort4*)(O + headbase + (size_t)t * Dc + df * 16 + g * 4) = o;
      }
    }
  }
#undef ISSUEK
#undef LOADV
#undef WRITEV
}

extern "C" void kernel_launch(void* const* d_in, const int* in_sizes, int n_in,
                              void* d_out, int out_size, void* d_ws, size_t ws_size,
                              hipStream_t stream) {
  (void)in_sizes; (void)n_in; (void)out_size; (void)ws_size;
  const float* x  = (const float*)d_in[0];
  const float* cs = (const float*)d_in[1];
  const float* sn = (const float*)d_in[2];
  // d_in[3] = mask (unused: causal handled analytically)
  const float* Wq = (const float*)d_in[4];
  const float* Wk = (const float*)d_in[5];
  const float* Wv = (const float*)d_in[6];
  const float* Wo = (const float*)d_in[7];
  float* out = (float*)d_out;

  char* ws = (char*)d_ws;
  const size_t MB = 1024 * 1024;
  ushort* xb  = (ushort*)(ws);            // 32MB x fp16; reused as attn output O
  ushort* wqb = (ushort*)(ws + 32 * MB);
  ushort* wkb = (ushort*)(ws + 40 * MB);
  ushort* wvb = (ushort*)(ws + 48 * MB);
  ushort* wob = (ushort*)(ws + 56 * MB);
  ushort* Qr  = (ushort*)(ws + 64 * MB);  // 32MB each, [B,T,H,128] fp16
  ushort* Kr  = (ushort*)(ws + 96 * MB);
  ushort* Vr  = (ushort*)(ws + 128 * MB); // end: 160MB

  cvt<<<16384, 256, 0, stream>>>(x, xb, 4194304);
  cvt<<<4096, 256, 0, stream>>>(Wq, wqb, 1048576);
  cvt<<<4096, 256, 0, stream>>>(Wk, wkb, 1048576);
  cvt<<<4096, 256, 0, stream>>>(Wv, wvb, 1048576);
  cvt<<<4096, 256, 0, stream>>>(Wo, wob, 1048576);

  const dim3 gg(16, 64);
  gemm_bt<ushort><<<gg, 256, 0, stream>>>(xb, wqb, Qr);
  gemm_bt<ushort><<<gg, 256, 0, stream>>>(xb, wkb, Kr);
  gemm_bt<ushort><<<gg, 256, 0, stream>>>(xb, wvb, Vr);

  rope<<<8192, 256, 0, stream>>>(Qr, cs, sn);
  rope<<<8192, 256, 0, stream>>>(Kr, cs, sn);

  attn<<<dim3(4, 64), 512, 0, stream>>>(Qr, Kr, Vr, xb);

  gemm_bt<float><<<gg, 256, 0, stream>>>(xb, wob, out);
}

// Round 8
// 538.817 us; speedup vs baseline: 1.2160x; 1.1366x over previous
//
#include <hip/hip_runtime.h>
#include <hip/hip_bf16.h>

#define DEV static __device__ __forceinline__

typedef __attribute__((ext_vector_type(8))) _Float16 half8;   // A/B frag: 8 fp16 = 4 VGPR
typedef __attribute__((ext_vector_type(4))) float f32x4;      // C/D frag

constexpr int Bc = 4, Tc = 2048, Dc = 2048, Hc = 16;          // HD = 128

DEV ushort f2h(float f) { _Float16 h = (_Float16)f; return __builtin_bit_cast(ushort, h); }
DEV float  h2f(ushort u) { return (float)__builtin_bit_cast(_Float16, u); }

DEV f32x4 MFMA(half8 a, half8 b, f32x4 c) {
  return __builtin_amdgcn_mfma_f32_16x16x32_f16(a, b, c, 0, 0, 0);
}

DEV void async_cp16(void* lds, const void* g) {
  __builtin_amdgcn_global_load_lds((const __attribute__((address_space(1))) void*)g,
                                   (__attribute__((address_space(3))) void*)lds,
                                   16, 0, 0);
}

// ---------------- f32 -> fp16 convert ----------------
__global__ __launch_bounds__(256) void cvt(const float* __restrict__ in,
                                           ushort* __restrict__ out, int n4) {
  const int i = blockIdx.x * 256 + threadIdx.x;
  if (i >= n4) return;
  const float4 v = ((const float4*)in)[i];
  ushort4 o;
  o.x = f2h(v.x); o.y = f2h(v.y); o.z = f2h(v.z); o.w = f2h(v.w);
  ((ushort4*)out)[i] = o;
}

// ---------------- GEMM 256x256, BK=32, triple-buffer counted-vmcnt ----------
// C[m][n] = sum_k A[m][k] * W[n][k]. 512 threads = 8 waves (2M x 4N), each
// wave owns 128x64 output (8x4 16x16 frags). LDS: 3 bufs x (A 16KB + B 16KB)
// = 96KB -> 1 block/CU, 2 waves/SIMD. Pipeline: compute buf[t%3] | barrier |
// stage t+3 into freed buf | vmcnt(8) [t+1 landed, t+2/t+3 IN FLIGHT] |
// barrier. Granule swizzle gl^=(row>>1)&3 (2-way max on ds_read_b128) with
// pre-swizzled global source. XCD owns 4 bm-panels (4MB A L2-resident).
template <typename OutT>
__global__ __launch_bounds__(512, 2) void gemm256(const ushort* __restrict__ A,
                                                  const ushort* __restrict__ Bw,
                                                  OutT* __restrict__ C) {
  __shared__ ushort As[3][256 * 32];
  __shared__ ushort Bs[3][256 * 32];
  const int tid = threadIdx.x;                 // 0..511
  const int lane = tid & 63, wid = tid >> 6;   // 8 waves
  const int g = lane >> 4, q16 = lane & 15;
  const int wm = wid >> 2, wn = wid & 3;       // 2M x 4N

  const int flat = (int)blockIdx.x;            // 0..255
  const int xcd = flat & 7, idx = flat >> 3;   // idx 0..31
  const int bm = xcd * 4 + (idx & 3);          // 0..31 (4 bm-panels per XCD)
  const int bn = idx >> 2;                     // 0..7
  const ushort* Ab = A + (size_t)bm * 256 * Dc;
  const ushort* Bb = Bw + (size_t)bn * 256 * Dc;

  // stage one 256x32 tile (16KB) = 2 x async_cp16 per thread; linear LDS dest,
  // inverse-swizzled source granule (rule #21 both-sides).
#define STAGE(P, K0, DST) do {                                                 \
    _Pragma("unroll") for (int p_ = 0; p_ < 2; ++p_) {                         \
      const int c_ = p_ * 512 + tid;                                           \
      const int row_ = c_ >> 2, gl_ = c_ & 3;                                  \
      async_cp16(&(DST)[(p_ * 512 + wid * 64) * 8],                            \
                 (P) + (size_t)row_ * Dc + (K0) +                              \
                 ((gl_ ^ ((row_ >> 1) & 3)) << 3));                            \
    }                                                                          \
  } while (0)

  f32x4 acc[8][4] = {};

  STAGE(Ab, 0, As[0]);  STAGE(Bb, 0, Bs[0]);
  STAGE(Ab, 32, As[1]); STAGE(Bb, 32, Bs[1]);
  STAGE(Ab, 64, As[2]); STAGE(Bb, 64, Bs[2]);
  asm volatile("s_waitcnt vmcnt(8)" ::: "memory");   // tile0 landed; 1,2 fly
  __builtin_amdgcn_s_barrier();
  __builtin_amdgcn_sched_barrier(0);

  // per-thread swizzled granule (constant: (row>>1)&3 == (q16>>1)&3)
  const int sgz = (g ^ ((q16 >> 1) & 3)) << 3;

  int buf = 0;
#pragma unroll 1
  for (int t = 0; t < 64; ++t) {
    const ushort* Asb = As[buf];
    const ushort* Bsb = Bs[buf];
    half8 af[8], bf[4];
#pragma unroll
    for (int mf = 0; mf < 8; ++mf) {
      const int r = wm * 128 + mf * 16 + q16;
      af[mf] = *(const half8*)&Asb[r * 32 + sgz];
    }
#pragma unroll
    for (int nf = 0; nf < 4; ++nf) {
      const int r = wn * 64 + nf * 16 + q16;
      bf[nf] = *(const half8*)&Bsb[r * 32 + sgz];
    }
    __builtin_amdgcn_s_setprio(1);
#pragma unroll
    for (int mf = 0; mf < 8; ++mf)
#pragma unroll
      for (int nf = 0; nf < 4; ++nf)
        acc[mf][nf] = MFMA(af[mf], bf[nf], acc[mf][nf]);
    __builtin_amdgcn_s_setprio(0);

    __builtin_amdgcn_s_barrier();          // all waves done reading buf
    __builtin_amdgcn_sched_barrier(0);
    if (t + 3 < 64) {
      STAGE(Ab, (t + 3) * 32, As[buf]);
      STAGE(Bb, (t + 3) * 32, Bs[buf]);
    }
    if (t + 3 < 64)      asm volatile("s_waitcnt vmcnt(8)" ::: "memory");
    else if (t + 2 < 64) asm volatile("s_waitcnt vmcnt(4)" ::: "memory");
    else                 asm volatile("s_waitcnt vmcnt(0)" ::: "memory");
    __builtin_amdgcn_s_barrier();          // t+1's tile globally visible
    __builtin_amdgcn_sched_barrier(0);
    buf = (buf == 2) ? 0 : buf + 1;
  }
#undef STAGE

  const int m00 = bm * 256 + wm * 128 + g * 4;
  const int n0 = bn * 256 + wn * 64 + q16;
#pragma unroll
  for (int mf = 0; mf < 8; ++mf)
#pragma unroll
    for (int nf = 0; nf < 4; ++nf) {
      const int m0 = m00 + mf * 16;
      const int n = n0 + nf * 16;
#pragma unroll
      for (int r = 0; r < 4; ++r) {
        const float v = acc[mf][nf][r];
        if constexpr (sizeof(OutT) == 2)
          C[(size_t)(m0 + r) * Dc + n] = (OutT)f2h(v);
        else
          C[(size_t)(m0 + r) * Dc + n] = (OutT)v;
      }
    }
}

// ---------------- RoPE in-place on [B,T,H,128] fp16 ----------------
__global__ __launch_bounds__(256) void rope(ushort* __restrict__ X,
                                            const float* __restrict__ cs,
                                            const float* __restrict__ sn) {
  const int tid = blockIdx.x * 256 + threadIdx.x;
  const int row = tid >> 4;
  const int jq = (tid & 15) << 2;
  const int t = (row >> 4) & (Tc - 1);
  ushort* base = X + (size_t)row * 128;
  const ushort4 lo = *(const ushort4*)(base + jq);
  const ushort4 hi = *(const ushort4*)(base + 64 + jq);
  const float4 c4 = *(const float4*)(cs + t * 128 + jq);
  const float4 s4 = *(const float4*)(sn + t * 128 + jq);
  const float xl[4] = {h2f(lo.x), h2f(lo.y), h2f(lo.z), h2f(lo.w)};
  const float xh[4] = {h2f(hi.x), h2f(hi.y), h2f(hi.z), h2f(hi.w)};
  const float cc[4] = {c4.x, c4.y, c4.z, c4.w};
  const float ss[4] = {s4.x, s4.y, s4.z, s4.w};
  ushort4 olo, ohi;
  ushort* po = (ushort*)&olo;
  ushort* ph = (ushort*)&ohi;
#pragma unroll
  for (int k = 0; k < 4; ++k) {
    po[k] = f2h(xl[k] * cc[k] - xh[k] * ss[k]);
    ph[k] = f2h(xh[k] * cc[k] + xl[k] * ss[k]);
  }
  *(ushort4*)(base + jq) = olo;
  *(ushort4*)(base + 64 + jq) = ohi;
}

// ---------------- causal flash attention (2 q-chains / wave) ----------------
// grid (4, 64) = 256 blocks (1/CU), 512 threads: 8 waves x 32 q-rows = 256-row
// supertile. Paired supertiles {7-p, p}. Two independent q-chains per wave
// interleave softmax stalls and share K/V LDS reads. Head-major XCD swizzle.
// LDS 64KB; in-register P redistribution; T13 defer-max; T14 V-stage split.
__global__ __launch_bounds__(512, 2) void attn(const ushort* __restrict__ Q,
                                               const ushort* __restrict__ K,
                                               const ushort* __restrict__ V,
                                               ushort* __restrict__ O) {
  __shared__ ushort Ks[2][64 * 128];   // [kv][d], XOR-swizzled (granule ^= kv&7)
  __shared__ ushort Vt[2][128 * 64];   // [d][kv], XOR-swizzled rows

  const int tid = threadIdx.x;         // 0..511
  const int lane = tid & 63, wid = tid >> 6;   // wid 0..7
  const int g = lane >> 4, q16 = lane & 15;

  // head-major XCD swizzle over 256 blocks
  const int flat = (int)(blockIdx.x + 4 * blockIdx.y);    // 0..255
  const int xcd = flat & 7, idx = flat >> 3;              // idx 0..31
  const int bh = xcd + 8 * (idx & 7);                     // head-slot 0..63
  const int pr = idx >> 3;                                // supertile pair 0..3

  const int b = bh >> 4, h = bh & 15;
  const size_t headbase = ((size_t)b * Tc * Hc + h) * 128;  // t-stride = 2048
  const float SCL2 = 0.12751743f;      // log2(e)/sqrt(128)

  // V lane mapping: dc spans 4 values per wave -> 4-way max on Vt ds_writes.
  const int vdc = (wid & 3) * 4 + (lane & 3);         // 0..15: d = vdc*8..+7
  const int vkvp = (wid >> 2) * 16 + (lane >> 2);     // 0..31: kv pair

  uint4 vreg[2];

#define ISSUEK(KT, BUF) do {                                                   \
    const ushort* Kb_ = K + headbase + (size_t)(KT) * 64 * Dc;                 \
    _Pragma("unroll") for (int i_ = 0; i_ < 2; ++i_) {                         \
      const int c_ = i_ * 512 + tid;                                           \
      const int kv_ = c_ >> 4, gl_ = c_ & 15;                                  \
      async_cp16(&Ks[BUF][(i_ * 512 + wid * 64) * 8],                          \
                 Kb_ + (size_t)kv_ * Dc + ((gl_ ^ (kv_ & 7)) << 3));           \
    }                                                                          \
  } while (0)

#define LOADV(KT) do {                                                         \
    const ushort* p0_ = V + headbase + (size_t)((KT) * 64 + 2 * vkvp) * Dc +   \
                        vdc * 8;                                               \
    vreg[0] = *(const uint4*)p0_;                                              \
    vreg[1] = *(const uint4*)(p0_ + Dc);                                       \
  } while (0)

#define WRITEV(BUF) do {                                                       \
    const ushort* e0_ = (const ushort*)&vreg[0];                               \
    const ushort* e1_ = (const ushort*)&vreg[1];                               \
    _Pragma("unroll") for (int j_ = 0; j_ < 8; ++j_) {                         \
      const int d_ = vdc * 8 + j_;                                             \
      const unsigned w_ = (unsigned)e0_[j_] | ((unsigned)e1_[j_] << 16);       \
      *(unsigned*)&Vt[BUF][(d_ * 64 + 2 * vkvp) ^ ((d_ & 7) << 3)] = w_;       \
    }                                                                          \
  } while (0)

#pragma unroll 1
  for (int half = 0; half < 2; ++half) {
    const int q0 = (half ? pr : 7 - pr) * 256;
    const int qrow = q0 + wid * 32;          // wave owns rows qrow..qrow+31
    const int nt = q0 / 64 + 4;

    // Q fragments, 2 chains (B-op: col=q=lane&15, k=d=g*8+j)
    half8 qreg[2][4];
#pragma unroll
    for (int qf = 0; qf < 2; ++qf)
#pragma unroll
      for (int ds = 0; ds < 4; ++ds)
        qreg[qf][ds] = *(const half8*)(Q + headbase +
                       (size_t)(qrow + qf * 16 + q16) * Dc + ds * 32 + g * 8);

    f32x4 oacc[2][8] = {};             // O^T frags: row=d (g*4+r), col=q
    float m_[2] = {-1e30f, -1e30f};
    float l_[2] = {0.f, 0.f};          // per-lane partials

    __builtin_amdgcn_s_barrier();      // prior half done reading all LDS bufs
    __builtin_amdgcn_sched_barrier(0);
    ISSUEK(0, 0);
    LOADV(0);
    WRITEV(0);                         // compiler waits vmcnt for vreg here

#pragma unroll 1
    for (int kt = 0; kt < nt; ++kt) {
      const int cur = kt & 1;
      const int kv0 = kt * 64;
      asm volatile("s_waitcnt vmcnt(0) lgkmcnt(0)" ::: "memory");
      __builtin_amdgcn_s_barrier();
      __builtin_amdgcn_sched_barrier(0);
      if (kt + 1 < nt) {
        ISSUEK(kt + 1, cur ^ 1);
        LOADV(kt + 1);
      }

      if (kv0 <= qrow + 31) {          // wave-uniform
        const ushort* Ksb = Ks[cur];
        const ushort* Vtb = Vt[cur];
        // S^T = K Q^T, both chains share kf
        f32x4 s[2][4] = {};
        __builtin_amdgcn_s_setprio(1);
#pragma unroll
        for (int ds = 0; ds < 4; ++ds) {
          half8 kf[4];
#pragma unroll
          for (int kvf = 0; kvf < 4; ++kvf) {
            const int kv = kvf * 16 + q16;
            kf[kvf] = *(const half8*)&Ksb[(kv * 128 + ds * 32 + g * 8) ^ ((kv & 7) << 3)];
          }
#pragma unroll
          for (int kvf = 0; kvf < 4; ++kvf)
#pragma unroll
            for (int qf = 0; qf < 2; ++qf)
              s[qf][kvf] = MFMA(kf[kvf], qreg[qf][ds], s[qf][kvf]);
        }
        __builtin_amdgcn_s_setprio(0);
        // causal mask + running max; mask only on diagonal tiles (uniform branch)
        float pmax[2] = {-1e30f, -1e30f};
        if (kv0 + 63 > qrow) {
#pragma unroll
          for (int qf = 0; qf < 2; ++qf) {
            const int qg = qrow + qf * 16 + q16;
#pragma unroll
            for (int kvf = 0; kvf < 4; ++kvf)
#pragma unroll
              for (int r = 0; r < 4; ++r) {
                float v = s[qf][kvf][r];
                if ((kv0 + kvf * 16 + g * 4 + r) > qg) v = -1e30f;
                s[qf][kvf][r] = v;
                pmax[qf] = fmaxf(pmax[qf], v);
              }
          }
        } else {
#pragma unroll
          for (int qf = 0; qf < 2; ++qf)
#pragma unroll
            for (int kvf = 0; kvf < 4; ++kvf)
#pragma unroll
              for (int r = 0; r < 4; ++r)
                pmax[qf] = fmaxf(pmax[qf], s[qf][kvf][r]);
        }
#pragma unroll
        for (int qf = 0; qf < 2; ++qf) {
          pmax[qf] = fmaxf(pmax[qf], __shfl_xor(pmax[qf], 16));
          pmax[qf] = fmaxf(pmax[qf], __shfl_xor(pmax[qf], 32));
        }
        // T13 defer-max (joint trigger; rescaling a non-growing chain is benign)
        if (!__all((pmax[0] <= m_[0] + 16.f) & (pmax[1] <= m_[1] + 16.f))) {
#pragma unroll
          for (int qf = 0; qf < 2; ++qf) {
            const float mn2 = fmaxf(m_[qf], pmax[qf]);
            const float alpha = __builtin_exp2f((m_[qf] - mn2) * SCL2);
            m_[qf] = mn2;
            l_[qf] *= alpha;
#pragma unroll
            for (int df = 0; df < 8; ++df)
              oacc[qf][df] *= alpha;
          }
        }
        // exp + pack, both chains
        uint w[2][4][2];
#pragma unroll
        for (int qf = 0; qf < 2; ++qf) {
          const float mn = m_[qf];
          float lsum = 0.f;
#pragma unroll
          for (int kvf = 0; kvf < 4; ++kvf) {
            const float p0 = __builtin_exp2f((s[qf][kvf][0] - mn) * SCL2);
            const float p1 = __builtin_exp2f((s[qf][kvf][1] - mn) * SCL2);
            const float p2 = __builtin_exp2f((s[qf][kvf][2] - mn) * SCL2);
            const float p3 = __builtin_exp2f((s[qf][kvf][3] - mn) * SCL2);
            lsum += (p0 + p1) + (p2 + p3);
            w[qf][kvf][0] = (unsigned)f2h(p0) | ((unsigned)f2h(p1) << 16);
            w[qf][kvf][1] = (unsigned)f2h(p2) | ((unsigned)f2h(p3) << 16);
          }
          l_[qf] += lsum;
        }
        // In-register P redistribution -> PV B-frags (per chain).
        const bool ghi = g >= 2;
        const bool godd = (g & 1) != 0;
        half8 pb[2][2];
#pragma unroll
        for (int qf = 0; qf < 2; ++qf) {
          uint sA[2][2], sB[2][2];
#pragma unroll
          for (int c = 0; c < 2; ++c)
#pragma unroll
            for (int i = 0; i < 2; ++i) {
              sA[c][i] = ghi ? w[qf][2 * c + 1][i] : w[qf][2 * c][i];
              sB[c][i] = ghi ? w[qf][2 * c][i] : w[qf][2 * c + 1][i];
            }
          uint x16[2][2], x32[2][2], x48[2][2];
#pragma unroll
          for (int c = 0; c < 2; ++c)
#pragma unroll
            for (int i = 0; i < 2; ++i) {
              x16[c][i] = __shfl_xor(sA[c][i], 16);
              x32[c][i] = __shfl_xor(sB[c][i], 32);
              x48[c][i] = __shfl_xor(sB[c][i], 48);
            }
#pragma unroll
          for (int c = 0; c < 2; ++c) {
            uint4 t;
            t.x = godd ? (ghi ? x16[c][0] : x48[c][0]) : (ghi ? x32[c][0] : sA[c][0]);
            t.y = godd ? (ghi ? x16[c][1] : x48[c][1]) : (ghi ? x32[c][1] : sA[c][1]);
            t.z = godd ? (ghi ? sA[c][0] : x32[c][0]) : (ghi ? x48[c][0] : x16[c][0]);
            t.w = godd ? (ghi ? sA[c][1] : x32[c][1]) : (ghi ? x48[c][1] : x16[c][1]);
            pb[qf][c] = __builtin_bit_cast(half8, t);
          }
        }
        // O^T += V^T P^T, both chains share vf
        __builtin_amdgcn_s_setprio(1);
#pragma unroll
        for (int c = 0; c < 2; ++c) {
#pragma unroll
          for (int df = 0; df < 8; ++df) {
            const int d = df * 16 + q16;
            const half8 vf = *(const half8*)&Vtb[(d * 64 + c * 32 + g * 8) ^ ((d & 7) << 3)];
#pragma unroll
            for (int qf = 0; qf < 2; ++qf)
              oacc[qf][df] = MFMA(vf, pb[qf][c], oacc[qf][df]);
          }
        }
        __builtin_amdgcn_s_setprio(0);
      }

      if (kt + 1 < nt) WRITEV(cur ^ 1);   // vreg vmcnt wait lands here, hidden
    }

    // epilogue: reduce per-lane l partials, store O fp16
#pragma unroll
    for (int qf = 0; qf < 2; ++qf) {
      float l = l_[qf];
      l += __shfl_xor(l, 16);
      l += __shfl_xor(l, 32);
      const float inv = 1.0f / l;
      const int t = qrow + qf * 16 + q16;
#pragma unroll
      for (int df = 0; df < 8; ++df) {
        const f32x4 v = oacc[qf][df];
        ushort4 o;
        o.x = f2h(v[0] * inv); o.y = f2h(v[1] * inv);
        o.z = f2h(v[2] * inv); o.w = f2h(v[3] * inv);
        *(ushort4*)(O + headbase + (size_t)t * Dc + df * 16 + g * 4) = o;
      }
    }
  }
#undef ISSUEK
#undef LOADV
#undef WRITEV
}

extern "C" void kernel_launch(void* const* d_in, const int* in_sizes, int n_in,
                              void* d_out, int out_size, void* d_ws, size_t ws_size,
                              hipStream_t stream) {
  (void)in_sizes; (void)n_in; (void)out_size; (void)ws_size;
  const float* x  = (const float*)d_in[0];
  const float* cs = (const float*)d_in[1];
  const float* sn = (const float*)d_in[2];
  // d_in[3] = mask (unused: causal handled analytically)
  const float* Wq = (const float*)d_in[4];
  const float* Wk = (const float*)d_in[5];
  const float* Wv = (const float*)d_in[6];
  const float* Wo = (const float*)d_in[7];
  float* out = (float*)d_out;

  char* ws = (char*)d_ws;
  const size_t MB = 1024 * 1024;
  ushort* xb  = (ushort*)(ws);            // 32MB x fp16; reused as attn output O
  ushort* wqb = (ushort*)(ws + 32 * MB);
  ushort* wkb = (ushort*)(ws + 40 * MB);
  ushort* wvb = (ushort*)(ws + 48 * MB);
  ushort* wob = (ushort*)(ws + 56 * MB);
  ushort* Qr  = (ushort*)(ws + 64 * MB);  // 32MB each, [B,T,H,128] fp16
  ushort* Kr  = (ushort*)(ws + 96 * MB);
  ushort* Vr  = (ushort*)(ws + 128 * MB); // end: 160MB

  cvt<<<16384, 256, 0, stream>>>(x, xb, 4194304);
  cvt<<<4096, 256, 0, stream>>>(Wq, wqb, 1048576);
  cvt<<<4096, 256, 0, stream>>>(Wk, wkb, 1048576);
  cvt<<<4096, 256, 0, stream>>>(Wv, wvb, 1048576);
  cvt<<<4096, 256, 0, stream>>>(Wo, wob, 1048576);

  gemm256<ushort><<<256, 512, 0, stream>>>(xb, wqb, Qr);
  gemm256<ushort><<<256, 512, 0, stream>>>(xb, wkb, Kr);
  gemm256<ushort><<<256, 512, 0, stream>>>(xb, wvb, Vr);

  rope<<<8192, 256, 0, stream>>>(Qr, cs, sn);
  rope<<<8192, 256, 0, stream>>>(Kr, cs, sn);

  attn<<<dim3(4, 64), 512, 0, stream>>>(Qr, Kr, Vr, xb);

  gemm256<float><<<256, 512, 0, stream>>>(xb, wob, out);
}

// Round 9
// 509.924 us; speedup vs baseline: 1.2849x; 1.0567x over previous
//
#include <hip/hip_runtime.h>
#include <hip/hip_bf16.h>

#define DEV static __device__ __forceinline__

typedef __attribute__((ext_vector_type(8))) _Float16 half8;   // A/B frag: 8 fp16 = 4 VGPR
typedef __attribute__((ext_vector_type(4))) float f32x4;      // C/D frag

constexpr int Bc = 4, Tc = 2048, Dc = 2048, Hc = 16;          // HD = 128

DEV ushort f2h(float f) { _Float16 h = (_Float16)f; return __builtin_bit_cast(ushort, h); }
DEV float  h2f(ushort u) { return (float)__builtin_bit_cast(_Float16, u); }

DEV f32x4 MFMA(half8 a, half8 b, f32x4 c) {
  return __builtin_amdgcn_mfma_f32_16x16x32_f16(a, b, c, 0, 0, 0);
}

DEV void async_cp16(void* lds, const void* g) {
  __builtin_amdgcn_global_load_lds((const __attribute__((address_space(1))) void*)g,
                                   (__attribute__((address_space(3))) void*)lds,
                                   16, 0, 0);
}

// ---------------- f32 -> fp16 convert ----------------
__global__ __launch_bounds__(256) void cvt(const float* __restrict__ in,
                                           ushort* __restrict__ out, int n4) {
  const int i = blockIdx.x * 256 + threadIdx.x;
  if (i >= n4) return;
  const float4 v = ((const float4*)in)[i];
  ushort4 o;
  o.x = f2h(v.x); o.y = f2h(v.y); o.z = f2h(v.z); o.w = f2h(v.w);
  ((ushort4*)out)[i] = o;
}

// ---------------- GEMM 256x256, BK=32, 4-slot ring, fine-phase pipeline ----
// C[m][n] = sum_k A[m][k]*W[n][k]. 512 threads = 8 waves (2M x 4N), wave owns
// 128x64 (8x4 frags). LDS: 4 ring slots x (A 16KB + B 16KB) = 128KB.
// Group t: compute buf[t%4], stage tile t+3 into buf[(t+3)%4] (freed after
// group t-1). 4 phases/group = one C-quadrant each: {ds_read 6|2 b128 (A/B
// frag reuse across phases) | 1 global_load_lds | vmcnt(8) | barrier |
// setprio(1) 8 MFMA setprio(0)}. Tile-t loads (phases 4t-12..4t-9) retire at
// phase-(4t-1) vmcnt(8), one barrier before group t's first read. Granule
// swizzle gl^((row>>1)&3) pre-swizzled src / g^((q16>>1)&3) read: 2-way max.
template <typename OutT>
__global__ __launch_bounds__(512, 2) void gemm256(const ushort* __restrict__ A,
                                                  const ushort* __restrict__ Bw,
                                                  OutT* __restrict__ C) {
  __shared__ ushort As[4][256 * 32];
  __shared__ ushort Bs[4][256 * 32];
  const int tid = threadIdx.x;                 // 0..511
  const int lane = tid & 63, wid = tid >> 6;   // 8 waves
  const int g = lane >> 4, q16 = lane & 15;
  const int wm = wid >> 2, wn = wid & 3;       // 2M x 4N

  const int flat = (int)blockIdx.x;            // 0..255
  const int xcd = flat & 7, idx = flat >> 3;   // idx 0..31
  const int bm = xcd * 4 + (idx & 3);          // 4 bm-panels per XCD
  const int bn = idx >> 2;                     // 0..7
  const ushort* Ab = A + (size_t)bm * 256 * Dc;
  const ushort* Bb = Bw + (size_t)bn * 256 * Dc;

  // One 16B staging load: PH 0/1 = A pass0/1, PH 2/3 = B pass0/1.
  // LDS granule index c = pass*512+tid <-> (row=c>>2, gslot=c&3); source
  // column-granule = gslot ^ ((row>>1)&3)  [inverse-swizzled source].
#define STAGE1(KT, BUF, PH) do {                                               \
    const int pass_ = (PH) & 1;                                                \
    const int c_ = pass_ * 512 + tid;                                          \
    const int row_ = c_ >> 2, gl_ = c_ & 3;                                    \
    const int col_ = (KT) * 32 + ((gl_ ^ ((row_ >> 1) & 3)) << 3);             \
    if ((PH) < 2)                                                              \
      async_cp16(&As[BUF][(pass_ * 512 + wid * 64) * 8],                       \
                 Ab + (size_t)row_ * Dc + col_);                               \
    else                                                                       \
      async_cp16(&Bs[BUF][(pass_ * 512 + wid * 64) * 8],                       \
                 Bb + (size_t)row_ * Dc + col_);                               \
  } while (0)

  f32x4 acc[8][4] = {};

  // prologue: tiles 0,1,2 -> slots 0,1,2 (12 loads), one-time drain
  for (int tt = 0; tt < 3; ++tt) {
    STAGE1(tt, tt, 0); STAGE1(tt, tt, 1);
    STAGE1(tt, tt, 2); STAGE1(tt, tt, 3);
  }
  asm volatile("s_waitcnt vmcnt(0)" ::: "memory");
  __builtin_amdgcn_s_barrier();
  __builtin_amdgcn_sched_barrier(0);

  const int sgz = (g ^ ((q16 >> 1) & 3)) << 3;   // read granule (ushort offset)

#define PHASE(AA, BB, RDA, RDB, PH) do {                                       \
    if (RDA) {                                                                 \
      _Pragma("unroll") for (int mf_ = 0; mf_ < 4; ++mf_) {                    \
        const int r_ = wm * 128 + (AA) * 64 + mf_ * 16 + q16;                  \
        af[mf_] = *(const half8*)&Asb[r_ * 32 + sgz];                          \
      }                                                                        \
    }                                                                          \
    if (RDB) {                                                                 \
      _Pragma("unroll") for (int nf_ = 0; nf_ < 2; ++nf_) {                    \
        const int r_ = wn * 64 + (BB) * 32 + nf_ * 16 + q16;                   \
        bf[nf_] = *(const half8*)&Bsb[r_ * 32 + sgz];                          \
      }                                                                        \
    }                                                                          \
    if (st) STAGE1(t + 3, sb, PH);                                             \
    asm volatile("s_waitcnt vmcnt(8)" ::: "memory");                           \
    __builtin_amdgcn_s_barrier();                                              \
    __builtin_amdgcn_sched_barrier(0);                                         \
    __builtin_amdgcn_s_setprio(1);                                             \
    _Pragma("unroll") for (int mf_ = 0; mf_ < 4; ++mf_)                        \
      _Pragma("unroll") for (int nf_ = 0; nf_ < 2; ++nf_)                      \
        acc[(AA) * 4 + mf_][(BB) * 2 + nf_] =                                  \
            MFMA(af[mf_], bf[nf_], acc[(AA) * 4 + mf_][(BB) * 2 + nf_]);       \
    __builtin_amdgcn_s_setprio(0);                                             \
  } while (0)

#pragma unroll 1
  for (int t = 0; t < 64; ++t) {
    const int rb = t & 3;              // read slot
    const int sb = (t + 3) & 3;        // stage slot (freed after group t-1)
    const bool st = (t + 3) < 64;
    const ushort* Asb = As[rb];
    const ushort* Bsb = Bs[rb];
    half8 af[4], bf[2];
    PHASE(0, 0, 1, 1, 0);   // quadrant (a0,b0): read A(a0)+B(b0)
    PHASE(0, 1, 0, 1, 1);   // (a0,b1): reuse A, read B(b1)
    PHASE(1, 1, 1, 0, 2);   // (a1,b1): read A(a1), reuse B
    PHASE(1, 0, 0, 1, 3);   // (a1,b0): read B(b0)
  }
#undef PHASE
#undef STAGE1

  const int m00 = bm * 256 + wm * 128 + g * 4;
  const int n0 = bn * 256 + wn * 64 + q16;
#pragma unroll
  for (int mf = 0; mf < 8; ++mf)
#pragma unroll
    for (int nf = 0; nf < 4; ++nf) {
      const int m0 = m00 + mf * 16;
      const int n = n0 + nf * 16;
#pragma unroll
      for (int r = 0; r < 4; ++r) {
        const float v = acc[mf][nf][r];
        if constexpr (sizeof(OutT) == 2)
          C[(size_t)(m0 + r) * Dc + n] = (OutT)f2h(v);
        else
          C[(size_t)(m0 + r) * Dc + n] = (OutT)v;
      }
    }
}

// ---------------- RoPE in-place on [B,T,H,128] fp16 ----------------
__global__ __launch_bounds__(256) void rope(ushort* __restrict__ X,
                                            const float* __restrict__ cs,
                                            const float* __restrict__ sn) {
  const int tid = blockIdx.x * 256 + threadIdx.x;
  const int row = tid >> 4;
  const int jq = (tid & 15) << 2;
  const int t = (row >> 4) & (Tc - 1);
  ushort* base = X + (size_t)row * 128;
  const ushort4 lo = *(const ushort4*)(base + jq);
  const ushort4 hi = *(const ushort4*)(base + 64 + jq);
  const float4 c4 = *(const float4*)(cs + t * 128 + jq);
  const float4 s4 = *(const float4*)(sn + t * 128 + jq);
  const float xl[4] = {h2f(lo.x), h2f(lo.y), h2f(lo.z), h2f(lo.w)};
  const float xh[4] = {h2f(hi.x), h2f(hi.y), h2f(hi.z), h2f(hi.w)};
  const float cc[4] = {c4.x, c4.y, c4.z, c4.w};
  const float ss[4] = {s4.x, s4.y, s4.z, s4.w};
  ushort4 olo, ohi;
  ushort* po = (ushort*)&olo;
  ushort* ph = (ushort*)&ohi;
#pragma unroll
  for (int k = 0; k < 4; ++k) {
    po[k] = f2h(xl[k] * cc[k] - xh[k] * ss[k]);
    ph[k] = f2h(xh[k] * cc[k] + xl[k] * ss[k]);
  }
  *(ushort4*)(base + jq) = olo;
  *(ushort4*)(base + 64 + jq) = ohi;
}

// ---------------- causal flash attention (2 q-chains / wave) ----------------
// grid (4, 64) = 256 blocks (1/CU), 512 threads: 8 waves x 32 q-rows = 256-row
// supertile. Paired supertiles {7-p, p}. Two independent q-chains per wave
// interleave softmax stalls and share K/V LDS reads. Head-major XCD swizzle.
// LDS 64KB; in-register P redistribution; T13 defer-max; T14 V-stage split.
__global__ __launch_bounds__(512, 2) void attn(const ushort* __restrict__ Q,
                                               const ushort* __restrict__ K,
                                               const ushort* __restrict__ V,
                                               ushort* __restrict__ O) {
  __shared__ ushort Ks[2][64 * 128];   // [kv][d], XOR-swizzled (granule ^= kv&7)
  __shared__ ushort Vt[2][128 * 64];   // [d][kv], XOR-swizzled rows

  const int tid = threadIdx.x;         // 0..511
  const int lane = tid & 63, wid = tid >> 6;   // wid 0..7
  const int g = lane >> 4, q16 = lane & 15;

  // head-major XCD swizzle over 256 blocks
  const int flat = (int)(blockIdx.x + 4 * blockIdx.y);    // 0..255
  const int xcd = flat & 7, idx = flat >> 3;              // idx 0..31
  const int bh = xcd + 8 * (idx & 7);                     // head-slot 0..63
  const int pr = idx >> 3;                                // supertile pair 0..3

  const int b = bh >> 4, h = bh & 15;
  const size_t headbase = ((size_t)b * Tc * Hc + h) * 128;  // t-stride = 2048
  const float SCL2 = 0.12751743f;      // log2(e)/sqrt(128)

  // V lane mapping: dc spans 4 values per wave -> 4-way max on Vt ds_writes.
  const int vdc = (wid & 3) * 4 + (lane & 3);         // 0..15: d = vdc*8..+7
  const int vkvp = (wid >> 2) * 16 + (lane >> 2);     // 0..31: kv pair

  uint4 vreg[2];

#define ISSUEK(KT, BUF) do {                                                   \
    const ushort* Kb_ = K + headbase + (size_t)(KT) * 64 * Dc;                 \
    _Pragma("unroll") for (int i_ = 0; i_ < 2; ++i_) {                         \
      const int c_ = i_ * 512 + tid;                                           \
      const int kv_ = c_ >> 4, gl_ = c_ & 15;                                  \
      async_cp16(&Ks[BUF][(i_ * 512 + wid * 64) * 8],                          \
                 Kb_ + (size_t)kv_ * Dc + ((gl_ ^ (kv_ & 7)) << 3));           \
    }                                                                          \
  } while (0)

#define LOADV(KT) do {                                                         \
    const ushort* p0_ = V + headbase + (size_t)((KT) * 64 + 2 * vkvp) * Dc +   \
                        vdc * 8;                                               \
    vreg[0] = *(const uint4*)p0_;                                              \
    vreg[1] = *(const uint4*)(p0_ + Dc);                                       \
  } while (0)

#define WRITEV(BUF) do {                                                       \
    const ushort* e0_ = (const ushort*)&vreg[0];                               \
    const ushort* e1_ = (const ushort*)&vreg[1];                               \
    _Pragma("unroll") for (int j_ = 0; j_ < 8; ++j_) {                         \
      const int d_ = vdc * 8 + j_;                                             \
      const unsigned w_ = (unsigned)e0_[j_] | ((unsigned)e1_[j_] << 16);       \
      *(unsigned*)&Vt[BUF][(d_ * 64 + 2 * vkvp) ^ ((d_ & 7) << 3)] = w_;       \
    }                                                                          \
  } while (0)

#pragma unroll 1
  for (int half = 0; half < 2; ++half) {
    const int q0 = (half ? pr : 7 - pr) * 256;
    const int qrow = q0 + wid * 32;          // wave owns rows qrow..qrow+31
    const int nt = q0 / 64 + 4;

    // Q fragments, 2 chains (B-op: col=q=lane&15, k=d=g*8+j)
    half8 qreg[2][4];
#pragma unroll
    for (int qf = 0; qf < 2; ++qf)
#pragma unroll
      for (int ds = 0; ds < 4; ++ds)
        qreg[qf][ds] = *(const half8*)(Q + headbase +
                       (size_t)(qrow + qf * 16 + q16) * Dc + ds * 32 + g * 8);

    f32x4 oacc[2][8] = {};             // O^T frags: row=d (g*4+r), col=q
    float m_[2] = {-1e30f, -1e30f};
    float l_[2] = {0.f, 0.f};          // per-lane partials

    __builtin_amdgcn_s_barrier();      // prior half done reading all LDS bufs
    __builtin_amdgcn_sched_barrier(0);
    ISSUEK(0, 0);
    LOADV(0);
    WRITEV(0);                         // compiler waits vmcnt for vreg here

#pragma unroll 1
    for (int kt = 0; kt < nt; ++kt) {
      const int cur = kt & 1;
      const int kv0 = kt * 64;
      asm volatile("s_waitcnt vmcnt(0) lgkmcnt(0)" ::: "memory");
      __builtin_amdgcn_s_barrier();
      __builtin_amdgcn_sched_barrier(0);
      if (kt + 1 < nt) {
        ISSUEK(kt + 1, cur ^ 1);
        LOADV(kt + 1);
      }

      if (kv0 <= qrow + 31) {          // wave-uniform
        const ushort* Ksb = Ks[cur];
        const ushort* Vtb = Vt[cur];
        // S^T = K Q^T, both chains share kf
        f32x4 s[2][4] = {};
        __builtin_amdgcn_s_setprio(1);
#pragma unroll
        for (int ds = 0; ds < 4; ++ds) {
          half8 kf[4];
#pragma unroll
          for (int kvf = 0; kvf < 4; ++kvf) {
            const int kv = kvf * 16 + q16;
            kf[kvf] = *(const half8*)&Ksb[(kv * 128 + ds * 32 + g * 8) ^ ((kv & 7) << 3)];
          }
#pragma unroll
          for (int kvf = 0; kvf < 4; ++kvf)
#pragma unroll
            for (int qf = 0; qf < 2; ++qf)
              s[qf][kvf] = MFMA(kf[kvf], qreg[qf][ds], s[qf][kvf]);
        }
        __builtin_amdgcn_s_setprio(0);
        // causal mask + running max; mask only on diagonal tiles (uniform branch)
        float pmax[2] = {-1e30f, -1e30f};
        if (kv0 + 63 > qrow) {
#pragma unroll
          for (int qf = 0; qf < 2; ++qf) {
            const int qg = qrow + qf * 16 + q16;
#pragma unroll
            for (int kvf = 0; kvf < 4; ++kvf)
#pragma unroll
              for (int r = 0; r < 4; ++r) {
                float v = s[qf][kvf][r];
                if ((kv0 + kvf * 16 + g * 4 + r) > qg) v = -1e30f;
                s[qf][kvf][r] = v;
                pmax[qf] = fmaxf(pmax[qf], v);
              }
          }
        } else {
#pragma unroll
          for (int qf = 0; qf < 2; ++qf)
#pragma unroll
            for (int kvf = 0; kvf < 4; ++kvf)
#pragma unroll
              for (int r = 0; r < 4; ++r)
                pmax[qf] = fmaxf(pmax[qf], s[qf][kvf][r]);
        }
#pragma unroll
        for (int qf = 0; qf < 2; ++qf) {
          pmax[qf] = fmaxf(pmax[qf], __shfl_xor(pmax[qf], 16));
          pmax[qf] = fmaxf(pmax[qf], __shfl_xor(pmax[qf], 32));
        }
        // T13 defer-max (joint trigger; rescaling a non-growing chain is benign)
        if (!__all((pmax[0] <= m_[0] + 16.f) & (pmax[1] <= m_[1] + 16.f))) {
#pragma unroll
          for (int qf = 0; qf < 2; ++qf) {
            const float mn2 = fmaxf(m_[qf], pmax[qf]);
            const float alpha = __builtin_exp2f((m_[qf] - mn2) * SCL2);
            m_[qf] = mn2;
            l_[qf] *= alpha;
#pragma unroll
            for (int df = 0; df < 8; ++df)
              oacc[qf][df] *= alpha;
          }
        }
        // exp + pack, both chains
        uint w[2][4][2];
#pragma unroll
        for (int qf = 0; qf < 2; ++qf) {
          const float mn = m_[qf];
          float lsum = 0.f;
#pragma unroll
          for (int kvf = 0; kvf < 4; ++kvf) {
            const float p0 = __builtin_exp2f((s[qf][kvf][0] - mn) * SCL2);
            const float p1 = __builtin_exp2f((s[qf][kvf][1] - mn) * SCL2);
            const float p2 = __builtin_exp2f((s[qf][kvf][2] - mn) * SCL2);
            const float p3 = __builtin_exp2f((s[qf][kvf][3] - mn) * SCL2);
            lsum += (p0 + p1) + (p2 + p3);
            w[qf][kvf][0] = (unsigned)f2h(p0) | ((unsigned)f2h(p1) << 16);
            w[qf][kvf][1] = (unsigned)f2h(p2) | ((unsigned)f2h(p3) << 16);
          }
          l_[qf] += lsum;
        }
        // In-register P redistribution -> PV B-frags (per chain).
        const bool ghi = g >= 2;
        const bool godd = (g & 1) != 0;
        half8 pb[2][2];
#pragma unroll
        for (int qf = 0; qf < 2; ++qf) {
          uint sA[2][2], sB[2][2];
#pragma unroll
          for (int c = 0; c < 2; ++c)
#pragma unroll
            for (int i = 0; i < 2; ++i) {
              sA[c][i] = ghi ? w[qf][2 * c + 1][i] : w[qf][2 * c][i];
              sB[c][i] = ghi ? w[qf][2 * c][i] : w[qf][2 * c + 1][i];
            }
          uint x16[2][2], x32[2][2], x48[2][2];
#pragma unroll
          for (int c = 0; c < 2; ++c)
#pragma unroll
            for (int i = 0; i < 2; ++i) {
              x16[c][i] = __shfl_xor(sA[c][i], 16);
              x32[c][i] = __shfl_xor(sB[c][i], 32);
              x48[c][i] = __shfl_xor(sB[c][i], 48);
            }
#pragma unroll
          for (int c = 0; c < 2; ++c) {
            uint4 t;
            t.x = godd ? (ghi ? x16[c][0] : x48[c][0]) : (ghi ? x32[c][0] : sA[c][0]);
            t.y = godd ? (ghi ? x16[c][1] : x48[c][1]) : (ghi ? x32[c][1] : sA[c][1]);
            t.z = godd ? (ghi ? sA[c][0] : x32[c][0]) : (ghi ? x48[c][0] : x16[c][0]);
            t.w = godd ? (ghi ? sA[c][1] : x32[c][1]) : (ghi ? x48[c][1] : x16[c][1]);
            pb[qf][c] = __builtin_bit_cast(half8, t);
          }
        }
        // O^T += V^T P^T, both chains share vf
        __builtin_amdgcn_s_setprio(1);
#pragma unroll
        for (int c = 0; c < 2; ++c) {
#pragma unroll
          for (int df = 0; df < 8; ++df) {
            const int d = df * 16 + q16;
            const half8 vf = *(const half8*)&Vtb[(d * 64 + c * 32 + g * 8) ^ ((d & 7) << 3)];
#pragma unroll
            for (int qf = 0; qf < 2; ++qf)
              oacc[qf][df] = MFMA(vf, pb[qf][c], oacc[qf][df]);
          }
        }
        __builtin_amdgcn_s_setprio(0);
      }

      if (kt + 1 < nt) WRITEV(cur ^ 1);   // vreg vmcnt wait lands here, hidden
    }

    // epilogue: reduce per-lane l partials, store O fp16
#pragma unroll
    for (int qf = 0; qf < 2; ++qf) {
      float l = l_[qf];
      l += __shfl_xor(l, 16);
      l += __shfl_xor(l, 32);
      const float inv = 1.0f / l;
      const int t = qrow + qf * 16 + q16;
#pragma unroll
      for (int df = 0; df < 8; ++df) {
        const f32x4 v = oacc[qf][df];
        ushort4 o;
        o.x = f2h(v[0] * inv); o.y = f2h(v[1] * inv);
        o.z = f2h(v[2] * inv); o.w = f2h(v[3] * inv);
        *(ushort4*)(O + headbase + (size_t)t * Dc + df * 16 + g * 4) = o;
      }
    }
  }
#undef ISSUEK
#undef LOADV
#undef WRITEV
}

extern "C" void kernel_launch(void* const* d_in, const int* in_sizes, int n_in,
                              void* d_out, int out_size, void* d_ws, size_t ws_size,
                              hipStream_t stream) {
  (void)in_sizes; (void)n_in; (void)out_size; (void)ws_size;
  const float* x  = (const float*)d_in[0];
  const float* cs = (const float*)d_in[1];
  const float* sn = (const float*)d_in[2];
  // d_in[3] = mask (unused: causal handled analytically)
  const float* Wq = (const float*)d_in[4];
  const float* Wk = (const float*)d_in[5];
  const float* Wv = (const float*)d_in[6];
  const float* Wo = (const float*)d_in[7];
  float* out = (float*)d_out;

  char* ws = (char*)d_ws;
  const size_t MB = 1024 * 1024;
  ushort* xb  = (ushort*)(ws);            // 32MB x fp16; reused as attn output O
  ushort* wqb = (ushort*)(ws + 32 * MB);
  ushort* wkb = (ushort*)(ws + 40 * MB);
  ushort* wvb = (ushort*)(ws + 48 * MB);
  ushort* wob = (ushort*)(ws + 56 * MB);
  ushort* Qr  = (ushort*)(ws + 64 * MB);  // 32MB each, [B,T,H,128] fp16
  ushort* Kr  = (ushort*)(ws + 96 * MB);
  ushort* Vr  = (ushort*)(ws + 128 * MB); // end: 160MB

  cvt<<<16384, 256, 0, stream>>>(x, xb, 4194304);
  cvt<<<4096, 256, 0, stream>>>(Wq, wqb, 1048576);
  cvt<<<4096, 256, 0, stream>>>(Wk, wkb, 1048576);
  cvt<<<4096, 256, 0, stream>>>(Wv, wvb, 1048576);
  cvt<<<4096, 256, 0, stream>>>(Wo, wob, 1048576);

  gemm256<ushort><<<256, 512, 0, stream>>>(xb, wqb, Qr);
  gemm256<ushort><<<256, 512, 0, stream>>>(xb, wkb, Kr);
  gemm256<ushort><<<256, 512, 0, stream>>>(xb, wvb, Vr);

  rope<<<8192, 256, 0, stream>>>(Qr, cs, sn);
  rope<<<8192, 256, 0, stream>>>(Kr, cs, sn);

  attn<<<dim3(4, 64), 512, 0, stream>>>(Qr, Kr, Vr, xb);

  gemm256<float><<<256, 512, 0, stream>>>(xb, wob, out);
}